// Round 2
// baseline (716.017 us; speedup 1.0000x reference)
//
#include <hip/hip_runtime.h>

#define NX 512
#define NY 512
#define NZ 256

typedef float v4f __attribute__((ext_vector_type(4)));

struct PtPrep {
    int b00, b01, b10, b11;   // float2-element indices of the 4 (ix,iy) z-pair lines
    float wx, wy, wz;
    bool valid;
};

__device__ __forceinline__ PtPrep prep(float px, float py, float pz,
                                       float lx, float ly, float lz,
                                       float rx, float ry, float rz) {
    PtPrep r;
    float fx = (px - lx) * rx;
    float fy = (py - ly) * ry;
    float fz = (pz - lz) * rz;
    r.valid = (fx >= 0.0f) && (fx <= (float)(NX - 1)) &&
              (fy >= 0.0f) && (fy <= (float)(NY - 1)) &&
              (fz >= 0.0f) && (fz <= (float)(NZ - 1));
    // clamp base so corner+1 is always in-bounds and z-pair is contiguous;
    // wx = fx - ix0 reproduces the reference's clamped interpolation exactly
    // (e.g. fx == NX-1: ix0 = NX-2, wx = 1.0 -> picks v[NX-1]).
    int ix0 = min(max((int)floorf(fx), 0), NX - 2);
    int iy0 = min(max((int)floorf(fy), 0), NY - 2);
    int iz0 = min(max((int)floorf(fz), 0), NZ - 2);
    r.wx = fx - (float)ix0;
    r.wy = fy - (float)iy0;
    r.wz = fz - (float)iz0;
    int row0 = (ix0 * NY + iy0) * NZ + iz0;
    // invalid lanes -> index 0: all aliases hit one cached line (L1 broadcast)
    r.b00 = r.valid ? row0 : 0;
    r.b01 = r.valid ? row0 + NZ : 0;            // (ix0, iy0+1)
    r.b10 = r.valid ? row0 + NY * NZ : 0;       // (ix0+1, iy0)
    r.b11 = r.valid ? row0 + NY * NZ + NZ : 0;  // (ix0+1, iy0+1)
    return r;
}

__device__ __forceinline__ void finish(const v4f& v00, const v4f& v01,
                                       const v4f& v10, const v4f& v11,
                                       const PtPrep& p, float& sigma, float& alpha) {
    float uz = 1.0f - p.wz, uy = 1.0f - p.wy, ux = 1.0f - p.wx;
    // v = {sigma(z0), alpha(z0), sigma(z1), alpha(z1)}
    float s00 = v00.x * uz + v00.z * p.wz;
    float a00 = v00.y * uz + v00.w * p.wz;
    float s01 = v01.x * uz + v01.z * p.wz;
    float a01 = v01.y * uz + v01.w * p.wz;
    float s10 = v10.x * uz + v10.z * p.wz;
    float a10 = v10.y * uz + v10.w * p.wz;
    float s11 = v11.x * uz + v11.z * p.wz;
    float a11 = v11.y * uz + v11.w * p.wz;
    sigma = ux * (uy * s00 + p.wy * s01) + p.wx * (uy * s10 + p.wy * s11);
    alpha = ux * (uy * a00 + p.wy * a01) + p.wx * (uy * a10 + p.wy * a11);
    if (!p.valid) { sigma = 0.0f; alpha = 0.0f; }
}

__global__ __launch_bounds__(256) void trilerp2_kernel(
    const float* __restrict__ x,
    const float* __restrict__ grid,
    const float* __restrict__ lower,
    const float* __restrict__ resolution,
    float* __restrict__ out,
    int n)
{
    int t = blockIdx.x * blockDim.x + threadIdx.x;
    int i0 = 2 * t;
    if (i0 >= n) return;
    bool has2 = (i0 + 1) < n;

    float lx = lower[0], ly = lower[1], lz = lower[2];
    float rx = resolution[0], ry = resolution[1], rz = resolution[2];

    const float* xp = x + 6 * (size_t)t;
    // point 0 (always fully in-bounds)
    float2 d0 = *(const float2*)xp;     // p0.x, p0.y  (8B aligned: 24t % 8 == 0)
    float p0x = d0.x, p0y = d0.y;
    float p0z = xp[2];
    // point 1 (guarded)
    float p1x = 0.0f, p1y = 0.0f, p1z = 0.0f;
    if (has2) { p1x = xp[3]; p1y = xp[4]; p1z = xp[5]; }

    PtPrep q0 = prep(p0x, p0y, p0z, lx, ly, lz, rx, ry, rz);
    PtPrep q1 = prep(p1x, p1y, p1z, lx, ly, lz, rx, ry, rz);

    const float2* g = (const float2*)grid;

    // issue all 8 independent 16B gathers before any consumption (max MLP)
    v4f A00, A01, A10, A11, B00, B01, B10, B11;
    __builtin_memcpy(&A00, g + q0.b00, 16);
    __builtin_memcpy(&A01, g + q0.b01, 16);
    __builtin_memcpy(&A10, g + q0.b10, 16);
    __builtin_memcpy(&A11, g + q0.b11, 16);
    __builtin_memcpy(&B00, g + q1.b00, 16);
    __builtin_memcpy(&B01, g + q1.b01, 16);
    __builtin_memcpy(&B10, g + q1.b10, 16);
    __builtin_memcpy(&B11, g + q1.b11, 16);

    float s0, a0, s1, a1;
    finish(A00, A01, A10, A11, q0, s0, a0);
    finish(B00, B01, B10, B11, q1, s1, a1);

    if (has2 && ((n & 1) == 0)) {
        *(float2*)(out + i0)     = make_float2(s0, s1);
        *(float2*)(out + n + i0) = make_float2(a0, a1);
    } else {
        out[i0] = s0;
        out[n + i0] = a0;
        if (has2) { out[i0 + 1] = s1; out[n + i0 + 1] = a1; }
    }
}

extern "C" void kernel_launch(void* const* d_in, const int* in_sizes, int n_in,
                              void* d_out, int out_size, void* d_ws, size_t ws_size,
                              hipStream_t stream) {
    const float* x          = (const float*)d_in[0];
    const float* grid       = (const float*)d_in[1];
    const float* lower      = (const float*)d_in[2];
    const float* resolution = (const float*)d_in[3];
    float* out              = (float*)d_out;

    int n = in_sizes[0] / 3;  // x is [N,3]
    int threads = (n + 1) / 2;
    int block = 256;
    int blocks = (threads + block - 1) / block;
    trilerp2_kernel<<<blocks, block, 0, stream>>>(x, grid, lower, resolution, out, n);
}